// Round 13
// baseline (390.996 us; speedup 1.0000x reference)
//
#include <hip/hip_runtime.h>
#include <math.h>

#define NPTS  4096
#define KNN   20
#define BLK   256
#define SPLIT 8
#define CHUNK (NPTS / SPLIT)   // 512 candidates per lane
#define PPB   (BLK / SPLIT)    // 32 points per block
#define QCAP  160              // = 8*KNN so queue region is reused for merge lists
#define NEGBIG -3.402823466e38f

// ---------- pass 1: stage (x,y,z,xx) as float4 in workspace ----------
__global__ __launch_bounds__(256) void stage_kernel(
    const float* __restrict__ x, float4* __restrict__ ws)
{
    const int i = blockIdx.x * 256 + threadIdx.x;   // over B*NPTS
    const int b = i >> 12;
    const int m = i & (NPTS - 1);
    const float* xb = x + (size_t)b * 3 * NPTS;
    {
        #pragma clang fp contract(off)
        const float a = xb[m];
        const float c = xb[NPTS + m];
        const float e = xb[2 * NPTS + m];
        // frozen np rounding: xx = ((a*a)+(c*c))+(e*e), per-op rounded, NO fma
        const float pa = a * a;
        const float pc = c * c;
        const float pe = e * e;
        const float s01 = pa + pc;
        const float xx = s01 + pe;
        ws[i] = make_float4(a, c, e, xx);
    }
}

// frozen np fp32 key: inner = fma(z,zm, fma(y,ym, x*xm)); v = (2i - xxm) - xxn
__device__ __forceinline__ float neg_dist(float xnf, float ynf, float znf,
                                          float xxn, float4 q)
{
    #pragma clang fp contract(off)
    const float p0    = xnf * q.x;
    const float f1    = __builtin_fmaf(ynf, q.y, p0);
    const float inner = __builtin_fmaf(znf, q.z, f1);
    const float two_i = inner + inner;
    const float tt    = two_i - q.w;
    return tt - xxn;
}

// stable sorted-insert, total order (v desc, idx asc) — explicit tie compare
#define INS_TIE(VV, II)                                                     \
    {                                                                       \
        bool cc_[KNN];                                                      \
        _Pragma("unroll")                                                   \
        for (int j_ = 0; j_ < KNN; ++j_)                                    \
            cc_[j_] = ((VV) > bv[j_]) || ((VV) == bv[j_] && (II) < bi[j_]); \
        _Pragma("unroll")                                                   \
        for (int j_ = KNN - 1; j_ >= 1; --j_) {                             \
            bv[j_] = cc_[j_] ? (cc_[j_ - 1] ? bv[j_ - 1] : (VV)) : bv[j_];  \
            bi[j_] = cc_[j_] ? (cc_[j_ - 1] ? bi[j_ - 1] : (II)) : bi[j_];  \
        }                                                                   \
        if (cc_[0]) { bv[0] = (VV); bi[0] = (II); }                         \
    }

__global__ __launch_bounds__(BLK, 3) void gap_layer_kernel(
    const float4* __restrict__ xs4,   // staged (x,y,z,xx), B*NPTS
    const float* __restrict__ w1,
    const float* __restrict__ g1, const float* __restrict__ be1,
    const float* __restrict__ mu1, const float* __restrict__ va1,
    const float* __restrict__ w2, const float* __restrict__ b2,
    const float* __restrict__ g2, const float* __restrict__ be2,
    const float* __restrict__ mu2, const float* __restrict__ va2,
    const float* __restrict__ w3, const float* __restrict__ b3,
    const float* __restrict__ g3, const float* __restrict__ be3,
    const float* __restrict__ mu3, const float* __restrict__ va3,
    float* __restrict__ out_ret,   // (B, N, 16) flat
    float* __restrict__ out_edge)  // (B, 16, N, KNN) flat
{
    __shared__ float2 qb[PPB * QCAP];   // 40 KB: queue, then merge lists
    __shared__ int    qcnt[PPB];
    __shared__ float4 wA[16], wE[16];
    __shared__ float  w3s[16];
    __shared__ float  fb3s;

    const int tid = threadIdx.x;
    const int p   = tid >> 3;      // local point 0..31 (8-lane group)
    const int c   = tid & 7;       // chunk / lane-in-group
    const int b     = blockIdx.x >> 7;            // 8 batches * 128 blocks
    const int nbase = (blockIdx.x & 127) * PPB;
    const int n     = nbase + p;

    if (tid < 16) {
        const int o = tid;
        float s1 = g1[o] * rsqrtf(va1[o] + 1e-5f);
        float fb1o = -mu1[o] * s1 + be1[o];
        wA[o] = make_float4(w1[o*3+0]*s1, w1[o*3+1]*s1, w1[o*3+2]*s1, fb1o);
        float s2 = g2[o] * rsqrtf(va2[o] + 1e-5f);
        float fb2o = (b2[o] - mu2[o]) * s2 + be2[o];
        wE[o] = make_float4(w2[o*3+0]*s2, w2[o*3+1]*s2, w2[o*3+2]*s2, fb2o);
        float s3 = g3[0] * rsqrtf(va3[0] + 1e-5f);
        w3s[o] = w3[o] * s3;
        if (o == 0) fb3s = (b3[0] - mu3[0]) * s3 + be3[0];
    }
    if (tid < PPB) qcnt[tid] = 0;
    __syncthreads();

    const float4* xb4 = xs4 + (size_t)b * NPTS;
    const float4 me = xb4[n];
    const float xnf = me.x, ynf = me.y, znf = me.z, xxn = me.w;

    // ---- phase 1: branch-free per-lane top-3 VALUES (no indices) ----
    float a0 = NEGBIG, a1 = NEGBIG, a2 = NEGBIG;
    #pragma unroll 4
    for (int t = 0; t < CHUNK; ++t) {
        const int m = (t << 3) | c;
        const float v = neg_dist(xnf, ynf, znf, xxn, xb4[m]);
        const bool c0 = v > a0, c1 = v > a1, c2 = v > a2;
        a2 = c2 ? (c1 ? a1 : v) : a2;
        a1 = c1 ? (c0 ? a0 : v) : a1;
        a0 = c0 ? v : a0;
    }
    // conservative admission threshold: min over group of 3rd-best
    // (every lane holds 3 items >= its a2 >= T  => >= 24 items >= T,
    //  so any item < T is beaten by >= 24 strictly greater -> not in top-20)
    float T = fminf(a2, __shfl_xor(a2, 1));
    T = fminf(T, __shfl_xor(T, 2));
    T = fminf(T, __shfl_xor(T, 4));

    // local exact 20-list (pads; also overflow fallback target)
    float bv[KNN];
    int   bi[KNN];
    #pragma unroll
    for (int j = 0; j < KNN; ++j) { bv[j] = NEGBIG; bi[j] = 0; }

    // ---- phase 2: rescan, admit v >= T into group queue ----
    #pragma unroll 4
    for (int t = 0; t < CHUNK; ++t) {
        const int m = (t << 3) | c;
        const float v = neg_dist(xnf, ynf, znf, xxn, xb4[m]);
        if (v >= T) {
            const int pos = atomicAdd(&qcnt[p], 1);
            if (pos < QCAP) {
                qb[p * QCAP + pos] = make_float2(v, __int_as_float(m));
            } else {
                INS_TIE(v, m);   // overflow fallback (rare): keep exact locally
            }
        }
    }

    // ---- phase 3: drain queue items j == c (mod 8) into local 20-list ----
    int L = *(volatile int*)&qcnt[p];
    L = (L < QCAP) ? L : QCAP;
    for (int j = c; j < L; j += 8) {
        const float vv = *(volatile float*)&qb[p * QCAP + j].x;
        const float mf = *(volatile float*)&qb[p * QCAP + j].y;
        const int   mm = __float_as_int(mf);
        INS_TIE(vv, mm);
    }

    // ---- phase 4: publish sorted lists into (reused) queue region ----
    {
        const int rb = p * QCAP + c * KNN;
        #pragma unroll
        for (int j = 0; j < KNN; ++j)
            qb[rb + j] = make_float2(bv[j], __int_as_float(bi[j]));
    }

    // ---- phase 5: 8-way tournament merge (v desc, idx asc);
    //      lane c records ranks r = c + 8j ----
    const int rb0 = p * QCAP;
    float2 h;
    h = qb[rb0 + 0*KNN]; float hv0 = h.x; int hi0 = __float_as_int(h.y);
    h = qb[rb0 + 1*KNN]; float hv1 = h.x; int hi1 = __float_as_int(h.y);
    h = qb[rb0 + 2*KNN]; float hv2 = h.x; int hi2 = __float_as_int(h.y);
    h = qb[rb0 + 3*KNN]; float hv3 = h.x; int hi3 = __float_as_int(h.y);
    h = qb[rb0 + 4*KNN]; float hv4 = h.x; int hi4 = __float_as_int(h.y);
    h = qb[rb0 + 5*KNN]; float hv5 = h.x; int hi5 = __float_as_int(h.y);
    h = qb[rb0 + 6*KNN]; float hv6 = h.x; int hi6 = __float_as_int(h.y);
    h = qb[rb0 + 7*KNN]; float hv7 = h.x; int hi7 = __float_as_int(h.y);
    int q0 = 1, q1 = 1, q2 = 1, q3 = 1, q4 = 1, q5 = 1, q6 = 1, q7 = 1;
    int mi0 = 0, mi1 = 0, mi2 = 0;

    #pragma unroll
    for (int r = 0; r < KNN; ++r) {
        const bool t01 = (hv1 > hv0) || (hv1 == hv0 && hi1 < hi0);
        float av = t01 ? hv1 : hv0; int ai = t01 ? hi1 : hi0; int aw = t01 ? 1 : 0;
        const bool t23 = (hv3 > hv2) || (hv3 == hv2 && hi3 < hi2);
        float bvv = t23 ? hv3 : hv2; int bii = t23 ? hi3 : hi2; int bw = t23 ? 3 : 2;
        const bool t45 = (hv5 > hv4) || (hv5 == hv4 && hi5 < hi4);
        float cv = t45 ? hv5 : hv4; int ci = t45 ? hi5 : hi4; int cw = t45 ? 5 : 4;
        const bool t67 = (hv7 > hv6) || (hv7 == hv6 && hi7 < hi6);
        float dv = t67 ? hv7 : hv6; int di = t67 ? hi7 : hi6; int dw = t67 ? 7 : 6;
        const bool tab = (bvv > av) || (bvv == av && bii < ai);
        float ev = tab ? bvv : av; int ei = tab ? bii : ai; int ew = tab ? bw : aw;
        const bool tcd = (dv > cv) || (dv == cv && di < ci);
        float fv = tcd ? dv : cv; int fi = tcd ? di : ci; int fw = tcd ? dw : cw;
        const bool tef = (fv > ev) || (fv == ev && fi < ei);
        const int wi = tef ? fi : ei;
        const int ww = tef ? fw : ew;

        {
            const int j = r >> 3;
            const bool mine = (c == (r & 7));
            mi0 = (mine && j == 0) ? wi : mi0;
            mi1 = (mine && j == 1) ? wi : mi1;
            mi2 = (mine && j == 2) ? wi : mi2;
        }

        int qw = (ww == 0) ? q0 : (ww == 1) ? q1 : (ww == 2) ? q2 : (ww == 3) ? q3
               : (ww == 4) ? q4 : (ww == 5) ? q5 : (ww == 6) ? q6 : q7;
        const int rd = (qw < KNN - 1) ? qw : (KNN - 1);
        const float2 nh = qb[rb0 + ww * KNN + rd];
        float nv = nh.x;
        const int ni = __float_as_int(nh.y);
        nv = (qw < KNN) ? nv : NEGBIG;
        q0 += (ww == 0); q1 += (ww == 1); q2 += (ww == 2); q3 += (ww == 3);
        q4 += (ww == 4); q5 += (ww == 5); q6 += (ww == 6); q7 += (ww == 7);
        hv0 = (ww == 0) ? nv : hv0;  hi0 = (ww == 0) ? ni : hi0;
        hv1 = (ww == 1) ? nv : hv1;  hi1 = (ww == 1) ? ni : hi1;
        hv2 = (ww == 2) ? nv : hv2;  hi2 = (ww == 2) ? ni : hi2;
        hv3 = (ww == 3) ? nv : hv3;  hi3 = (ww == 3) ? ni : hi3;
        hv4 = (ww == 4) ? nv : hv4;  hi4 = (ww == 4) ? ni : hi4;
        hv5 = (ww == 5) ? nv : hv5;  hi5 = (ww == 5) ? ni : hi5;
        hv6 = (ww == 6) ? nv : hv6;  hi6 = (ww == 6) ? ni : hi6;
        hv7 = (ww == 7) ? nv : hv7;  hi7 = (ww == 7) ? ni : hi7;
    }

    // ---- edge diffs for this lane's ranks (k = c + 8j; j=2 only for c<4) ----
    const bool has3 = (c < 4);
    float d0[3], d1[3], d2[3];
    {
        const int mjs[3] = { mi0, mi1, mi2 };
        #pragma unroll
        for (int j = 0; j < 3; ++j) {
            const float4 q = xb4[mjs[j]];
            d0[j] = xnf - q.x;
            d1[j] = ynf - q.y;
            d2[j] = znf - q.z;
        }
    }

    // ---- attention logits + edge_feature output ----
    float sacc[3] = {0.f, 0.f, 0.f}, nacc[3] = {0.f, 0.f, 0.f};
    const float fb3 = fb3s;
    for (int o = 0; o < 16; ++o) {
        const float4 wa = wA[o];
        const float4 we = wE[o];
        const float w3o = w3s[o];
        const size_t ebase = (((size_t)b * 16 + o) * NPTS + n) * KNN + c;
        #pragma unroll
        for (int j = 0; j < 3; ++j) {
            float f1 = fmaf(d2[j], wa.z, fmaf(d1[j], wa.y, fmaf(d0[j], wa.x, wa.w)));
            f1 = fmaxf(f1, 0.f);
            sacc[j] = fmaf(f1, w3o, sacc[j]);
            float ee = fmaf(d2[j], we.z, fmaf(d1[j], we.y, fmaf(d0[j], we.x, we.w)));
            ee = fmaxf(ee, 0.f);
            nacc[j] = fmaf(ee, w3o, nacc[j]);
            if (j < 2) out_edge[ebase + 8 * j] = ee;
            else if (has3) out_edge[ebase + 16] = ee;
        }
    }

    // ---- leaky_relu + softmax over k (8-lane group = one point) ----
    float att[3];
    float mx = NEGBIG;
    #pragma unroll
    for (int j = 0; j < 3; ++j) {
        float l = fmaxf(sacc[j] + fb3, 0.f) + fmaxf(nacc[j] + fb3, 0.f);
        l = (l >= 0.f) ? l : 0.01f * l;
        att[j] = l;
        if (j < 2 || has3) mx = fmaxf(mx, l);
    }
    mx = fmaxf(mx, __shfl_xor(mx, 1));
    mx = fmaxf(mx, __shfl_xor(mx, 2));
    mx = fmaxf(mx, __shfl_xor(mx, 4));
    float sum = 0.f;
    #pragma unroll
    for (int j = 0; j < 3; ++j) {
        float e = expf(att[j] - mx);
        if (j == 2 && !has3) e = 0.f;
        att[j] = e;
        sum += e;
    }
    sum += __shfl_xor(sum, 1);
    sum += __shfl_xor(sum, 2);
    sum += __shfl_xor(sum, 4);
    const float inv = 1.f / sum;
    #pragma unroll
    for (int j = 0; j < 3; ++j) att[j] *= inv;

    // ---- weighted edge sum (recompute edge), group-reduce, elu, write ret ----
    float val[16];
    for (int o = 0; o < 16; ++o) {
        const float4 we = wE[o];
        float v = 0.f;
        #pragma unroll
        for (int j = 0; j < 3; ++j) {
            float ee = fmaf(d2[j], we.z, fmaf(d1[j], we.y, fmaf(d0[j], we.x, we.w)));
            ee = fmaxf(ee, 0.f);
            v = fmaf(att[j], ee, v);
        }
        val[o] = v;
    }
    #pragma unroll
    for (int o = 0; o < 16; ++o) {
        val[o] += __shfl_xor(val[o], 1);
        val[o] += __shfl_xor(val[o], 2);
        val[o] += __shfl_xor(val[o], 4);
    }
    const size_t rbase = ((size_t)b * NPTS + n) * 16;
    #pragma unroll
    for (int oi = 0; oi < 2; ++oi) {
        const int o = 2 * c + oi;
        const float vv = val[o];
        out_ret[rbase + o] = (vv > 0.f) ? vv : expm1f(vv);
    }
}

extern "C" void kernel_launch(void* const* d_in, const int* in_sizes, int n_in,
                              void* d_out, int out_size, void* d_ws, size_t ws_size,
                              hipStream_t stream) {
    (void)n_in; (void)out_size; (void)ws_size;
    const float* x   = (const float*)d_in[0];
    const float* w1  = (const float*)d_in[1];
    const float* g1  = (const float*)d_in[2];
    const float* be1 = (const float*)d_in[3];
    const float* mu1 = (const float*)d_in[4];
    const float* va1 = (const float*)d_in[5];
    const float* w2  = (const float*)d_in[6];
    const float* b2  = (const float*)d_in[7];
    const float* g2  = (const float*)d_in[8];
    const float* be2 = (const float*)d_in[9];
    const float* mu2 = (const float*)d_in[10];
    const float* va2 = (const float*)d_in[11];
    const float* w3  = (const float*)d_in[12];
    const float* b3  = (const float*)d_in[13];
    const float* g3  = (const float*)d_in[14];
    const float* be3 = (const float*)d_in[15];
    const float* mu3 = (const float*)d_in[16];
    const float* va3 = (const float*)d_in[17];

    const int B = in_sizes[0] / (3 * NPTS);   // = 8
    float* out_ret  = (float*)d_out;                          // B*N*16
    float* out_edge = out_ret + (size_t)B * NPTS * 16;        // B*16*N*K

    float4* xs4 = (float4*)d_ws;              // B*NPTS float4 = 512 KB

    stage_kernel<<<B * NPTS / 256, 256, 0, stream>>>(x, xs4);

    const int grid = B * (NPTS / PPB);        // 8 * 128 = 1024 blocks
    gap_layer_kernel<<<grid, BLK, 0, stream>>>(
        xs4, w1, g1, be1, mu1, va1, w2, b2, g2, be2, mu2, va2,
        w3, b3, g3, be3, mu3, va3, out_ret, out_edge);
}

// Round 14
// 305.456 us; speedup vs baseline: 1.2800x; 1.2800x over previous
//
#include <hip/hip_runtime.h>
#include <math.h>

#define NPTS  4096
#define KNN   20
#define BLK   256
#define SPLIT 8
#define CHUNK (NPTS / SPLIT)   // 512 candidates per lane
#define PPB   (BLK / SPLIT)    // 32 points per block
#define QCAP  128              // queue slots per point (float2)
#define RSTRIDE 1040           // union region stride (bytes): >=1024, 8B-aligned, breaks pow2 banks
#define NEGBIG -3.402823466e38f

// ---------- pass 1: stage (x,y,z,xx) as float4 in workspace ----------
__global__ __launch_bounds__(256) void stage_kernel(
    const float* __restrict__ x, float4* __restrict__ ws)
{
    const int i = blockIdx.x * 256 + threadIdx.x;   // over B*NPTS
    const int b = i >> 12;
    const int m = i & (NPTS - 1);
    const float* xb = x + (size_t)b * 3 * NPTS;
    {
        #pragma clang fp contract(off)
        const float a = xb[m];
        const float c = xb[NPTS + m];
        const float e = xb[2 * NPTS + m];
        // frozen np rounding: xx = ((a*a)+(c*c))+(e*e), per-op rounded, NO fma
        const float pa = a * a;
        const float pc = c * c;
        const float pe = e * e;
        const float s01 = pa + pc;
        const float xx = s01 + pe;
        ws[i] = make_float4(a, c, e, xx);
    }
}

// frozen np fp32 key: inner = fma(z,zm, fma(y,ym, x*xm)); v = (2i - xxm) - xxn
__device__ __forceinline__ float neg_dist(float xnf, float ynf, float znf,
                                          float xxn, float4 q)
{
    #pragma clang fp contract(off)
    const float p0    = xnf * q.x;
    const float f1    = __builtin_fmaf(ynf, q.y, p0);
    const float inner = __builtin_fmaf(znf, q.z, f1);
    const float two_i = inner + inner;
    const float tt    = two_i - q.w;
    return tt - xxn;
}

// stable sorted-insert, total order (v desc, idx asc) — explicit tie compare
#define INS_TIE(VV, II)                                                     \
    {                                                                       \
        bool cc_[KNN];                                                      \
        _Pragma("unroll")                                                   \
        for (int j_ = 0; j_ < KNN; ++j_)                                    \
            cc_[j_] = ((VV) > bv[j_]) || ((VV) == bv[j_] && (II) < bi[j_]); \
        _Pragma("unroll")                                                   \
        for (int j_ = KNN - 1; j_ >= 1; --j_) {                             \
            bv[j_] = cc_[j_] ? (cc_[j_ - 1] ? bv[j_ - 1] : (VV)) : bv[j_];  \
            bi[j_] = cc_[j_] ? (cc_[j_ - 1] ? bi[j_ - 1] : (II)) : bi[j_];  \
        }                                                                   \
        if (cc_[0]) { bv[0] = (VV); bi[0] = (II); }                         \
    }

__global__ __launch_bounds__(BLK, 4) void gap_layer_kernel(
    const float4* __restrict__ xs4,   // staged (x,y,z,xx), B*NPTS
    const float* __restrict__ w1,
    const float* __restrict__ g1, const float* __restrict__ be1,
    const float* __restrict__ mu1, const float* __restrict__ va1,
    const float* __restrict__ w2, const float* __restrict__ b2,
    const float* __restrict__ g2, const float* __restrict__ be2,
    const float* __restrict__ mu2, const float* __restrict__ va2,
    const float* __restrict__ w3, const float* __restrict__ b3,
    const float* __restrict__ g3, const float* __restrict__ be3,
    const float* __restrict__ mu3, const float* __restrict__ va3,
    float* __restrict__ out_ret,   // (B, N, 16) flat
    float* __restrict__ out_edge)  // (B, 16, N, KNN) flat
{
    // per-point union region: [0,1024) queue of float2; after the drain it is
    // reused as merge lists: sv float[160] at 0, si u16[160] at 640.
    __shared__ char   region[PPB * RSTRIDE];   // 33,280 B
    __shared__ int    qcnt[PPB];
    __shared__ float4 wA[16], wE[16];
    __shared__ float  w3s[16];
    __shared__ float  fb3s;

    const int tid = threadIdx.x;
    const int p   = tid >> 3;      // local point 0..31 (8-lane group)
    const int c   = tid & 7;       // chunk / lane-in-group
    const int b     = blockIdx.x >> 7;            // 8 batches * 128 blocks
    const int nbase = (blockIdx.x & 127) * PPB;
    const int n     = nbase + p;

    if (tid < 16) {
        const int o = tid;
        float s1 = g1[o] * rsqrtf(va1[o] + 1e-5f);
        float fb1o = -mu1[o] * s1 + be1[o];
        wA[o] = make_float4(w1[o*3+0]*s1, w1[o*3+1]*s1, w1[o*3+2]*s1, fb1o);
        float s2 = g2[o] * rsqrtf(va2[o] + 1e-5f);
        float fb2o = (b2[o] - mu2[o]) * s2 + be2[o];
        wE[o] = make_float4(w2[o*3+0]*s2, w2[o*3+1]*s2, w2[o*3+2]*s2, fb2o);
        float s3 = g3[0] * rsqrtf(va3[0] + 1e-5f);
        w3s[o] = w3[o] * s3;
        if (o == 0) fb3s = (b3[0] - mu3[0]) * s3 + be3[0];
    }
    if (tid < PPB) qcnt[tid] = 0;
    __syncthreads();

    float2*         qq  = (float2*)&region[p * RSTRIDE];
    float*          svp = (float*)&region[p * RSTRIDE];
    unsigned short* sip = (unsigned short*)&region[p * RSTRIDE + 640];

    const float4* xb4 = xs4 + (size_t)b * NPTS;
    const float4 me = xb4[n];
    const float xnf = me.x, ynf = me.y, znf = me.z, xxn = me.w;

    // ---- phase 1: branch-free per-lane top-3 VALUES, 2 independent chains ----
    float a0 = NEGBIG, a1 = NEGBIG, a2 = NEGBIG;   // even t
    float e0 = NEGBIG, e1 = NEGBIG, e2 = NEGBIG;   // odd t
    #pragma unroll 4
    for (int t = 0; t < CHUNK; t += 2) {
        const int mA = (t << 3) | c;
        const int mB = ((t + 1) << 3) | c;
        const float vA = neg_dist(xnf, ynf, znf, xxn, xb4[mA]);
        const float vB = neg_dist(xnf, ynf, znf, xxn, xb4[mB]);
        {
            const bool c0 = vA > a0, c1 = vA > a1, c2 = vA > a2;
            a2 = c2 ? (c1 ? a1 : vA) : a2;
            a1 = c1 ? (c0 ? a0 : vA) : a1;
            a0 = c0 ? vA : a0;
        }
        {
            const bool c0 = vB > e0, c1 = vB > e1, c2 = vB > e2;
            e2 = c2 ? (c1 ? e1 : vB) : e2;
            e1 = c1 ? (c0 ? e0 : vB) : e1;
            e0 = c0 ? vB : e0;
        }
    }
    // merge odd chain into even chain (values only)
    {
        const float mv[3] = { e0, e1, e2 };
        #pragma unroll
        for (int j = 0; j < 3; ++j) {
            const float v = mv[j];
            const bool c0 = v > a0, c1 = v > a1, c2 = v > a2;
            a2 = c2 ? (c1 ? a1 : v) : a2;
            a1 = c1 ? (c0 ? a0 : v) : a1;
            a0 = c0 ? v : a0;
        }
    }
    // conservative admission threshold: min over group of 3rd-best
    // (8 lanes x 3 items >= T  =>  >=24 items >= T  =>  anything < T is out)
    float T = fminf(a2, __shfl_xor(a2, 1));
    T = fminf(T, __shfl_xor(T, 2));
    T = fminf(T, __shfl_xor(T, 4));

    // local exact 20-list (pads; also overflow fallback target)
    float bv[KNN];
    int   bi[KNN];
    #pragma unroll
    for (int j = 0; j < KNN; ++j) { bv[j] = NEGBIG; bi[j] = 0; }

    // ---- phase 2: rescan, admit v >= T into group queue ----
    #pragma unroll 8
    for (int t = 0; t < CHUNK; ++t) {
        const int m = (t << 3) | c;
        const float v = neg_dist(xnf, ynf, znf, xxn, xb4[m]);
        if (v >= T) {
            const int pos = atomicAdd(&qcnt[p], 1);
            if (pos < QCAP) {
                qq[pos] = make_float2(v, __int_as_float(m));
            } else {
                INS_TIE(v, m);   // overflow fallback (rare): keep exact locally
            }
        }
    }

    // ---- phase 3: drain queue items j == c (mod 8) into local 20-list ----
    int L = *(volatile int*)&qcnt[p];
    L = (L < QCAP) ? L : QCAP;
    for (int j = c; j < L; j += 8) {
        const float vv = *(volatile float*)&qq[j].x;
        const float mf = *(volatile float*)&qq[j].y;
        const int   mm = __float_as_int(mf);
        INS_TIE(vv, mm);
    }
    __syncthreads();   // region reuse boundary (queue -> merge lists)

    // ---- phase 4: publish sorted lists (split float / u16) ----
    {
        const int rb = c * KNN;
        #pragma unroll
        for (int j = 0; j < KNN; ++j) {
            svp[rb + j] = bv[j];
            sip[rb + j] = (unsigned short)bi[j];
        }
    }

    // ---- phase 5: 8-way tournament merge (v desc, idx asc);
    //      lane c records ranks r = c + 8j ----
    float hv0 = svp[0*KNN]; int hi0 = sip[0*KNN];
    float hv1 = svp[1*KNN]; int hi1 = sip[1*KNN];
    float hv2 = svp[2*KNN]; int hi2 = sip[2*KNN];
    float hv3 = svp[3*KNN]; int hi3 = sip[3*KNN];
    float hv4 = svp[4*KNN]; int hi4 = sip[4*KNN];
    float hv5 = svp[5*KNN]; int hi5 = sip[5*KNN];
    float hv6 = svp[6*KNN]; int hi6 = sip[6*KNN];
    float hv7 = svp[7*KNN]; int hi7 = sip[7*KNN];
    int q0 = 1, q1 = 1, q2 = 1, q3 = 1, q4 = 1, q5 = 1, q6 = 1, q7 = 1;
    int mi0 = 0, mi1 = 0, mi2 = 0;

    #pragma unroll
    for (int r = 0; r < KNN; ++r) {
        const bool t01 = (hv1 > hv0) || (hv1 == hv0 && hi1 < hi0);
        float av = t01 ? hv1 : hv0; int ai = t01 ? hi1 : hi0; int aw = t01 ? 1 : 0;
        const bool t23 = (hv3 > hv2) || (hv3 == hv2 && hi3 < hi2);
        float bvv = t23 ? hv3 : hv2; int bii = t23 ? hi3 : hi2; int bw = t23 ? 3 : 2;
        const bool t45 = (hv5 > hv4) || (hv5 == hv4 && hi5 < hi4);
        float cv = t45 ? hv5 : hv4; int ci = t45 ? hi5 : hi4; int cw = t45 ? 5 : 4;
        const bool t67 = (hv7 > hv6) || (hv7 == hv6 && hi7 < hi6);
        float dv = t67 ? hv7 : hv6; int di = t67 ? hi7 : hi6; int dw = t67 ? 7 : 6;
        const bool tab = (bvv > av) || (bvv == av && bii < ai);
        float ev = tab ? bvv : av; int ei = tab ? bii : ai; int ew = tab ? bw : aw;
        const bool tcd = (dv > cv) || (dv == cv && di < ci);
        float fv = tcd ? dv : cv; int fi = tcd ? di : ci; int fw = tcd ? dw : cw;
        const bool tef = (fv > ev) || (fv == ev && fi < ei);
        const int wi = tef ? fi : ei;
        const int ww = tef ? fw : ew;

        {
            const int j = r >> 3;
            const bool mine = (c == (r & 7));
            mi0 = (mine && j == 0) ? wi : mi0;
            mi1 = (mine && j == 1) ? wi : mi1;
            mi2 = (mine && j == 2) ? wi : mi2;
        }

        int qw = (ww == 0) ? q0 : (ww == 1) ? q1 : (ww == 2) ? q2 : (ww == 3) ? q3
               : (ww == 4) ? q4 : (ww == 5) ? q5 : (ww == 6) ? q6 : q7;
        const int rd = (qw < KNN - 1) ? qw : (KNN - 1);
        float nv = svp[ww * KNN + rd];
        const int ni = sip[ww * KNN + rd];
        nv = (qw < KNN) ? nv : NEGBIG;
        q0 += (ww == 0); q1 += (ww == 1); q2 += (ww == 2); q3 += (ww == 3);
        q4 += (ww == 4); q5 += (ww == 5); q6 += (ww == 6); q7 += (ww == 7);
        hv0 = (ww == 0) ? nv : hv0;  hi0 = (ww == 0) ? ni : hi0;
        hv1 = (ww == 1) ? nv : hv1;  hi1 = (ww == 1) ? ni : hi1;
        hv2 = (ww == 2) ? nv : hv2;  hi2 = (ww == 2) ? ni : hi2;
        hv3 = (ww == 3) ? nv : hv3;  hi3 = (ww == 3) ? ni : hi3;
        hv4 = (ww == 4) ? nv : hv4;  hi4 = (ww == 4) ? ni : hi4;
        hv5 = (ww == 5) ? nv : hv5;  hi5 = (ww == 5) ? ni : hi5;
        hv6 = (ww == 6) ? nv : hv6;  hi6 = (ww == 6) ? ni : hi6;
        hv7 = (ww == 7) ? nv : hv7;  hi7 = (ww == 7) ? ni : hi7;
    }

    // ---- edge diffs for this lane's ranks (k = c + 8j; j=2 only for c<4) ----
    const bool has3 = (c < 4);
    float d0[3], d1[3], d2[3];
    {
        const int mjs[3] = { mi0, mi1, mi2 };
        #pragma unroll
        for (int j = 0; j < 3; ++j) {
            const float4 q = xb4[mjs[j]];
            d0[j] = xnf - q.x;
            d1[j] = ynf - q.y;
            d2[j] = znf - q.z;
        }
    }

    // ---- attention logits + edge_feature output ----
    float sacc[3] = {0.f, 0.f, 0.f}, nacc[3] = {0.f, 0.f, 0.f};
    const float fb3 = fb3s;
    for (int o = 0; o < 16; ++o) {
        const float4 wa = wA[o];
        const float4 we = wE[o];
        const float w3o = w3s[o];
        const size_t ebase = (((size_t)b * 16 + o) * NPTS + n) * KNN + c;
        #pragma unroll
        for (int j = 0; j < 3; ++j) {
            float f1 = fmaf(d2[j], wa.z, fmaf(d1[j], wa.y, fmaf(d0[j], wa.x, wa.w)));
            f1 = fmaxf(f1, 0.f);
            sacc[j] = fmaf(f1, w3o, sacc[j]);
            float ee = fmaf(d2[j], we.z, fmaf(d1[j], we.y, fmaf(d0[j], we.x, we.w)));
            ee = fmaxf(ee, 0.f);
            nacc[j] = fmaf(ee, w3o, nacc[j]);
            if (j < 2) out_edge[ebase + 8 * j] = ee;
            else if (has3) out_edge[ebase + 16] = ee;
        }
    }

    // ---- leaky_relu + softmax over k (8-lane group = one point) ----
    float att[3];
    float mx = NEGBIG;
    #pragma unroll
    for (int j = 0; j < 3; ++j) {
        float l = fmaxf(sacc[j] + fb3, 0.f) + fmaxf(nacc[j] + fb3, 0.f);
        l = (l >= 0.f) ? l : 0.01f * l;
        att[j] = l;
        if (j < 2 || has3) mx = fmaxf(mx, l);
    }
    mx = fmaxf(mx, __shfl_xor(mx, 1));
    mx = fmaxf(mx, __shfl_xor(mx, 2));
    mx = fmaxf(mx, __shfl_xor(mx, 4));
    float sum = 0.f;
    #pragma unroll
    for (int j = 0; j < 3; ++j) {
        float e = expf(att[j] - mx);
        if (j == 2 && !has3) e = 0.f;
        att[j] = e;
        sum += e;
    }
    sum += __shfl_xor(sum, 1);
    sum += __shfl_xor(sum, 2);
    sum += __shfl_xor(sum, 4);
    const float inv = 1.f / sum;
    #pragma unroll
    for (int j = 0; j < 3; ++j) att[j] *= inv;

    // ---- weighted edge sum (recompute edge), group-reduce, elu, write ret ----
    float val[16];
    for (int o = 0; o < 16; ++o) {
        const float4 we = wE[o];
        float v = 0.f;
        #pragma unroll
        for (int j = 0; j < 3; ++j) {
            float ee = fmaf(d2[j], we.z, fmaf(d1[j], we.y, fmaf(d0[j], we.x, we.w)));
            ee = fmaxf(ee, 0.f);
            v = fmaf(att[j], ee, v);
        }
        val[o] = v;
    }
    #pragma unroll
    for (int o = 0; o < 16; ++o) {
        val[o] += __shfl_xor(val[o], 1);
        val[o] += __shfl_xor(val[o], 2);
        val[o] += __shfl_xor(val[o], 4);
    }
    const size_t rbase = ((size_t)b * NPTS + n) * 16;
    #pragma unroll
    for (int oi = 0; oi < 2; ++oi) {
        const int o = 2 * c + oi;
        const float vv = val[o];
        out_ret[rbase + o] = (vv > 0.f) ? vv : expm1f(vv);
    }
}

extern "C" void kernel_launch(void* const* d_in, const int* in_sizes, int n_in,
                              void* d_out, int out_size, void* d_ws, size_t ws_size,
                              hipStream_t stream) {
    (void)n_in; (void)out_size; (void)ws_size;
    const float* x   = (const float*)d_in[0];
    const float* w1  = (const float*)d_in[1];
    const float* g1  = (const float*)d_in[2];
    const float* be1 = (const float*)d_in[3];
    const float* mu1 = (const float*)d_in[4];
    const float* va1 = (const float*)d_in[5];
    const float* w2  = (const float*)d_in[6];
    const float* b2  = (const float*)d_in[7];
    const float* g2  = (const float*)d_in[8];
    const float* be2 = (const float*)d_in[9];
    const float* mu2 = (const float*)d_in[10];
    const float* va2 = (const float*)d_in[11];
    const float* w3  = (const float*)d_in[12];
    const float* b3  = (const float*)d_in[13];
    const float* g3  = (const float*)d_in[14];
    const float* be3 = (const float*)d_in[15];
    const float* mu3 = (const float*)d_in[16];
    const float* va3 = (const float*)d_in[17];

    const int B = in_sizes[0] / (3 * NPTS);   // = 8
    float* out_ret  = (float*)d_out;                          // B*N*16
    float* out_edge = out_ret + (size_t)B * NPTS * 16;        // B*16*N*K

    float4* xs4 = (float4*)d_ws;              // B*NPTS float4 = 512 KB

    stage_kernel<<<B * NPTS / 256, 256, 0, stream>>>(x, xs4);

    const int grid = B * (NPTS / PPB);        // 8 * 128 = 1024 blocks
    gap_layer_kernel<<<grid, BLK, 0, stream>>>(
        xs4, w1, g1, be1, mu1, va1, w2, b2, g2, be2, mu2, va2,
        w3, b3, g3, be3, mu3, va3, out_ret, out_edge);
}